// Round 1
// baseline (46.507 us; speedup 1.0000x reference)
//
#include <hip/hip_runtime.h>
#include <hip/hip_bf16.h>

#define EPS 1e-07f
#define SQRT_2PI 2.5066282746310002f

#define BLOCK 256
#define SLICE 128   // Gaussians per K-slice staged in LDS

// ---------------------------------------------------------------------------
// Kernel 1: per-Gaussian precompute (K threads).
// Packs: gA[k] = {m00, m01, m11, conc*sqrt(2pi)}
//        gB[k] = {Sm0, Sm1, mSm, 0}
// ---------------------------------------------------------------------------
__global__ void precompute_gauss(const float* __restrict__ pos_raw,
                                 const float* __restrict__ conc_raw,
                                 const float* __restrict__ scale_raw,
                                 const float* __restrict__ rot_raw,
                                 const void*  __restrict__ map_size_p,
                                 float4* __restrict__ gA,
                                 float4* __restrict__ gB,
                                 int K)
{
    int k = blockIdx.x * blockDim.x + threadIdx.x;
    if (k >= K) return;

    // map_size may arrive as int32 or float32 single-element array.
    // Decode robustly: if the bits form a sane float, use it; else treat as int.
    unsigned int msbits = *(const unsigned int*)map_size_p;
    float msf = __uint_as_float(msbits);
    float ms;
    if (msf >= 1e-3f && msf <= 1e9f) ms = msf;
    else                             ms = (float)(*(const int*)map_size_p);

    float pr0 = pos_raw[2*k],  pr1 = pos_raw[2*k+1];
    float pos0 = ms / (1.0f + expf(-pr0));   // sigmoid * map_size
    float pos1 = ms / (1.0f + expf(-pr1));

    float cr = conc_raw[k];
    // stable softplus: max(x,0) + log1p(exp(-|x|))
    float conc = fmaxf(cr, 0.0f) + log1pf(expf(-fabsf(cr)));

    float s0 = expf(scale_raw[2*k]);
    float s1 = expf(scale_raw[2*k+1]);
    float d0 = 1.0f / (s0*s0 + EPS);
    float d1 = 1.0f / (s1*s1 + EPS);

    float rot = rot_raw[k];
    float c = cosf(rot), s = sinf(rot);

    float m00 = c*c*d0 + s*s*d1;
    float m01 = c*s*(d0 - d1);
    float m11 = s*s*d0 + c*c*d1;

    float Sm0 = m00*pos0 + m01*pos1;
    float Sm1 = m01*pos0 + m11*pos1;
    float mSm = pos0*Sm0 + pos1*Sm1;

    gA[k] = make_float4(m00, m01, m11, conc * SQRT_2PI);
    gB[k] = make_float4(Sm0, Sm1, mSm, 0.0f);
}

// ---------------------------------------------------------------------------
// Kernel 2: main pairwise accumulation.
// grid = (R/BLOCK, K/SLICE); each block stages SLICE Gaussians into LDS and
// each thread (one ray) loops them with uniform-address (broadcast) LDS reads.
// One atomicAdd per (ray, slice).
// ---------------------------------------------------------------------------
__global__ __launch_bounds__(BLOCK) void splat_main(
        const float* __restrict__ p_rays,
        const float* __restrict__ u_rays,
        const float4* __restrict__ gA,
        const float4* __restrict__ gB,
        float* __restrict__ out,
        int K)
{
    __shared__ float4 sA[SLICE];
    __shared__ float4 sB[SLICE];

    const int ray = blockIdx.x * BLOCK + threadIdx.x;
    const int k0  = blockIdx.y * SLICE;
    const int nk  = min(SLICE, K - k0);

    // Cooperative stage: 256 threads, 256 float4 total (128 A + 128 B).
    {
        int t = threadIdx.x;
        if (t < SLICE) {
            if (t < nk) sA[t] = gA[k0 + t];
        } else {
            int j = t - SLICE;
            if (j < nk) sB[j] = gB[k0 + j];
        }
    }
    __syncthreads();

    float2 p2 = *(const float2*)(p_rays + 2*ray);
    float2 u2 = *(const float2*)(u_rays + 2*ray);
    const float p0 = p2.x, p1 = p2.y;
    const float u0 = u2.x, u1 = u2.y;

    const float qu0 = u0*u0, qu1 = 2.0f*u0*u1, qu2 = u1*u1;
    const float qp0 = p0*p0, qp1 = 2.0f*p0*p1, qp2 = p1*p1;
    const float qv0 = u0*p0, qv1 = u0*p1 + u1*p0, qv2 = u1*p1;

    float acc = 0.0f;

    #pragma unroll 4
    for (int j = 0; j < nk; ++j) {
        float4 ga = sA[j];     // broadcast (uniform address)
        float4 gb = sB[j];

        float a   = qu0*ga.x + qu1*ga.y + qu2*ga.z;
        float pSp = qp0*ga.x + qp1*ga.y + qp2*ga.z;
        float uSp = qv0*ga.x + qv1*ga.y + qv2*ga.z;

        float uSm = u0*gb.x + u1*gb.y;
        float pSm = p0*gb.x + p1*gb.y;

        float b  = uSp - uSm;
        float c0 = pSp - 2.0f*pSm + gb.z;

        float ra  = rsqrtf(a);           // 1/sqrt(a)
        float bra = b * ra;
        float t   = c0 - bra*bra;        // c0 - b^2/a

        acc += ga.w * ra * __expf(-0.5f * t);
    }

    atomicAdd(&out[ray], acc);
}

// ---------------------------------------------------------------------------
extern "C" void kernel_launch(void* const* d_in, const int* in_sizes, int n_in,
                              void* d_out, int out_size, void* d_ws, size_t ws_size,
                              hipStream_t stream)
{
    const float* pos_raw   = (const float*)d_in[0];
    const float* conc_raw  = (const float*)d_in[1];
    const float* scale_raw = (const float*)d_in[2];
    const float* rot_raw   = (const float*)d_in[3];
    const float* p_rays    = (const float*)d_in[4];
    const float* u_rays    = (const float*)d_in[5];
    const void*  map_size  = d_in[6];

    const int K = in_sizes[1];          // conc_raw is (K,)
    const int R = out_size;             // output is (R,)

    float* out = (float*)d_out;
    float4* gA = (float4*)d_ws;                     // K float4
    float4* gB = (float4*)d_ws + K;                 // K float4   (total 32*K bytes)

    // Zero output (we accumulate with atomics).
    hipMemsetAsync(d_out, 0, (size_t)R * sizeof(float), stream);

    // Precompute per-Gaussian parameters.
    {
        dim3 grid((K + BLOCK - 1) / BLOCK);
        precompute_gauss<<<grid, BLOCK, 0, stream>>>(pos_raw, conc_raw, scale_raw,
                                                     rot_raw, map_size, gA, gB, K);
    }

    // Main pairwise kernel.
    {
        dim3 grid(R / BLOCK, (K + SLICE - 1) / SLICE);
        splat_main<<<grid, BLOCK, 0, stream>>>(p_rays, u_rays, gA, gB, out, K);
    }
}

// Round 2
// 33.350 us; speedup vs baseline: 1.3945x; 1.3945x over previous
//
#include <hip/hip_runtime.h>
#include <hip/hip_bf16.h>

#define EPS 1e-07f

#define BLOCK 256
#define SLICE 64            // Gaussians per K-slice (grid.y)

// L = -0.5 * log2(e); s = sqrt(-L); log2(sqrt(2*pi))
#define NEG_HALF_LOG2E  (-0.72134752044448170f)
#define SQRT_HALF_LOG2E ( 0.84932180028801904f)
#define LOG2_SQRT_2PI   ( 1.32574806473616588f)

// ---------------------------------------------------------------------------
// Kernel 1: per-Gaussian precompute (K threads).
//   gA[k] = {m00, m01, m11, cc}   cc = L*mSm + log2(conc) + log2(sqrt(2pi))
//   gB[k] = {Sm0, Sm1}
// ---------------------------------------------------------------------------
__global__ void precompute_gauss(const float* __restrict__ pos_raw,
                                 const float* __restrict__ conc_raw,
                                 const float* __restrict__ scale_raw,
                                 const float* __restrict__ rot_raw,
                                 const void*  __restrict__ map_size_p,
                                 float4* __restrict__ gA,
                                 float2* __restrict__ gB,
                                 int K)
{
    int k = blockIdx.x * blockDim.x + threadIdx.x;
    if (k >= K) return;

    // map_size may arrive as int32 or float32 single-element array.
    unsigned int msbits = *(const unsigned int*)map_size_p;
    float msf = __uint_as_float(msbits);
    float ms;
    if (msf >= 1e-3f && msf <= 1e9f) ms = msf;
    else                             ms = (float)(*(const int*)map_size_p);

    float pr0 = pos_raw[2*k],  pr1 = pos_raw[2*k+1];
    float pos0 = ms / (1.0f + expf(-pr0));   // sigmoid * map_size
    float pos1 = ms / (1.0f + expf(-pr1));

    float cr = conc_raw[k];
    float conc = fmaxf(cr, 0.0f) + log1pf(expf(-fabsf(cr)));   // stable softplus

    float s0 = expf(scale_raw[2*k]);
    float s1 = expf(scale_raw[2*k+1]);
    float d0 = 1.0f / (s0*s0 + EPS);
    float d1 = 1.0f / (s1*s1 + EPS);

    float rot = rot_raw[k];
    float c = cosf(rot), s = sinf(rot);

    float m00 = c*c*d0 + s*s*d1;
    float m01 = c*s*(d0 - d1);
    float m11 = s*s*d0 + c*c*d1;

    float Sm0 = m00*pos0 + m01*pos1;
    float Sm1 = m01*pos0 + m11*pos1;
    float mSm = pos0*Sm0 + pos1*Sm1;

    float cc = NEG_HALF_LOG2E * mSm + log2f(conc) + LOG2_SQRT_2PI;

    gA[k] = make_float4(m00, m01, m11, cc);
    gB[k] = make_float2(Sm0, Sm1);
}

// ---------------------------------------------------------------------------
// Kernel 2: main pairwise accumulation.
//   dens = rsqrt(a) * 2^( cc + L*c0_part + (b~ * rsqrt(a))^2 )
// where ray-side coefficients are pre-scaled by L and s = sqrt(-L) so the
// inner loop is 13 FMA + rsq + mul + fma + exp2 + fmac = 18 VALU instrs.
// Gaussian reads are wave-uniform -> scalar loads (no LDS, no syncthreads).
// ---------------------------------------------------------------------------
__global__ __launch_bounds__(BLOCK) void splat_main(
        const float* __restrict__ p_rays,
        const float* __restrict__ u_rays,
        const float4* __restrict__ gA,
        const float2* __restrict__ gB,
        float* __restrict__ out,
        int K)
{
    const int ray = blockIdx.x * BLOCK + threadIdx.x;
    const int k0  = blockIdx.y * SLICE;
    const int k1  = min(k0 + SLICE, K);

    float2 p2 = *(const float2*)(p_rays + 2*ray);
    float2 u2 = *(const float2*)(u_rays + 2*ray);
    const float p0 = p2.x, p1 = p2.y;
    const float u0 = u2.x, u1 = u2.y;

    // a-dot coefficients (unscaled)
    const float qu0 = u0*u0, qu1 = 2.0f*u0*u1, qu2 = u1*u1;

    // b~ coefficients, scaled by s = sqrt(-L)
    const float bq0  =  SQRT_HALF_LOG2E * u0*p0;
    const float bq1  =  SQRT_HALF_LOG2E * (u0*p1 + u1*p0);
    const float bq2  =  SQRT_HALF_LOG2E * u1*p1;
    const float nbu0 = -SQRT_HALF_LOG2E * u0;
    const float nbu1 = -SQRT_HALF_LOG2E * u1;

    // c0 coefficients, scaled by L (constant term comes from gA.w)
    const float cq0 =  NEG_HALF_LOG2E * p0*p0;
    const float cq1 =  NEG_HALF_LOG2E * 2.0f*p0*p1;
    const float cq2 =  NEG_HALF_LOG2E * p1*p1;
    const float cp0 = -2.0f*NEG_HALF_LOG2E * p0;
    const float cp1 = -2.0f*NEG_HALF_LOG2E * p1;

    float acc = 0.0f;

    #pragma unroll 8
    for (int j = k0; j < k1; ++j) {
        float4 ga = gA[j];   // wave-uniform -> scalar load
        float2 gb = gB[j];

        float a   = fmaf(qu2, ga.z, fmaf(qu1, ga.y, qu0 * ga.x));
        float bt  = fmaf(nbu1, gb.y, fmaf(nbu0, gb.x,
                    fmaf(bq2, ga.z, fmaf(bq1, ga.y, bq0 * ga.x))));
        float c2  = fmaf(cp1, gb.y, fmaf(cp0, gb.x,
                    fmaf(cq2, ga.z, fmaf(cq1, ga.y, fmaf(cq0, ga.x, ga.w)))));

        float ra  = __builtin_amdgcn_rsqf(a);
        float t1  = bt * ra;
        float arg = fmaf(t1, t1, c2);
        float e   = __builtin_amdgcn_exp2f(arg);
        acc = fmaf(ra, e, acc);
    }

    atomicAdd(&out[ray], acc);
}

// ---------------------------------------------------------------------------
extern "C" void kernel_launch(void* const* d_in, const int* in_sizes, int n_in,
                              void* d_out, int out_size, void* d_ws, size_t ws_size,
                              hipStream_t stream)
{
    const float* pos_raw   = (const float*)d_in[0];
    const float* conc_raw  = (const float*)d_in[1];
    const float* scale_raw = (const float*)d_in[2];
    const float* rot_raw   = (const float*)d_in[3];
    const float* p_rays    = (const float*)d_in[4];
    const float* u_rays    = (const float*)d_in[5];
    const void*  map_size  = d_in[6];

    const int K = in_sizes[1];          // conc_raw is (K,)
    const int R = out_size;             // output is (R,)

    float* out = (float*)d_out;
    float4* gA = (float4*)d_ws;                       // K float4
    float2* gB = (float2*)((float4*)d_ws + K);        // K float2  (24*K bytes)

    hipMemsetAsync(d_out, 0, (size_t)R * sizeof(float), stream);

    {
        dim3 grid((K + BLOCK - 1) / BLOCK);
        precompute_gauss<<<grid, BLOCK, 0, stream>>>(pos_raw, conc_raw, scale_raw,
                                                     rot_raw, map_size, gA, gB, K);
    }
    {
        dim3 grid(R / BLOCK, (K + SLICE - 1) / SLICE);
        splat_main<<<grid, BLOCK, 0, stream>>>(p_rays, u_rays, gA, gB, out, K);
    }
}

// Round 3
// 26.413 us; speedup vs baseline: 1.7608x; 1.2627x over previous
//
#include <hip/hip_runtime.h>
#include <hip/hip_bf16.h>

#define EPS 1e-07f

#define BLOCK 256
#define SLICE 64            // Gaussians per K-slice (grid.y)

// L = -0.5 * log2(e); s = sqrt(-L); log2(sqrt(2*pi))
#define NEG_HALF_LOG2E  (-0.72134752044448170f)
#define SQRT_HALF_LOG2E ( 0.84932180028801904f)
#define LOG2_SQRT_2PI   ( 1.32574806473616588f)

// ---------------------------------------------------------------------------
// Kernel 1: per-Gaussian precompute (K threads) + zero d_out.
//   gA[k] = {m00, m01, m11, cc}   cc = L*mSm + log2(conc) + log2(sqrt(2pi))
//   gB[k] = {Sm0, Sm1}
// Ordering: launched before splat_main on the same stream, so the zeroed
// output is visible to splat_main's atomics.
// ---------------------------------------------------------------------------
__global__ void precompute_gauss(const float* __restrict__ pos_raw,
                                 const float* __restrict__ conc_raw,
                                 const float* __restrict__ scale_raw,
                                 const float* __restrict__ rot_raw,
                                 const void*  __restrict__ map_size_p,
                                 float4* __restrict__ gA,
                                 float2* __restrict__ gB,
                                 float*  __restrict__ out,
                                 int K, int R)
{
    int k = blockIdx.x * blockDim.x + threadIdx.x;
    int nthreads = gridDim.x * blockDim.x;

    // Zero the output (replaces hipMemsetAsync dispatch).
    for (int i = k; i < R; i += nthreads) out[i] = 0.0f;

    if (k >= K) return;

    // map_size may arrive as int32 or float32 single-element array.
    unsigned int msbits = *(const unsigned int*)map_size_p;
    float msf = __uint_as_float(msbits);
    float ms;
    if (msf >= 1e-3f && msf <= 1e9f) ms = msf;
    else                             ms = (float)(*(const int*)map_size_p);

    float pr0 = pos_raw[2*k],  pr1 = pos_raw[2*k+1];
    float pos0 = ms / (1.0f + expf(-pr0));   // sigmoid * map_size
    float pos1 = ms / (1.0f + expf(-pr1));

    float cr = conc_raw[k];
    float conc = fmaxf(cr, 0.0f) + log1pf(expf(-fabsf(cr)));   // stable softplus

    float s0 = expf(scale_raw[2*k]);
    float s1 = expf(scale_raw[2*k+1]);
    float d0 = 1.0f / (s0*s0 + EPS);
    float d1 = 1.0f / (s1*s1 + EPS);

    float rot = rot_raw[k];
    float c = cosf(rot), s = sinf(rot);

    float m00 = c*c*d0 + s*s*d1;
    float m01 = c*s*(d0 - d1);
    float m11 = s*s*d0 + c*c*d1;

    float Sm0 = m00*pos0 + m01*pos1;
    float Sm1 = m01*pos0 + m11*pos1;
    float mSm = pos0*Sm0 + pos1*Sm1;

    float cc = NEG_HALF_LOG2E * mSm + log2f(conc) + LOG2_SQRT_2PI;

    gA[k] = make_float4(m00, m01, m11, cc);
    gB[k] = make_float2(Sm0, Sm1);
}

// ---------------------------------------------------------------------------
// Kernel 2: main pairwise accumulation.
//   dens = rsqrt(a) * 2^( cc + L*c0_part + (b~ * rsqrt(a))^2 )
// Gaussian slice staged in LDS; inner-loop reads are wave-uniform addresses
// (pure broadcast, conflict-free, off the L1 path). 16 VALU + 2 trans / pair.
// ---------------------------------------------------------------------------
__global__ __launch_bounds__(BLOCK) void splat_main(
        const float* __restrict__ p_rays,
        const float* __restrict__ u_rays,
        const float4* __restrict__ gA,
        const float2* __restrict__ gB,
        float* __restrict__ out,
        int K)
{
    __shared__ float4 sA[SLICE];
    __shared__ float2 sB[SLICE];

    const int ray = blockIdx.x * BLOCK + threadIdx.x;
    const int k0  = blockIdx.y * SLICE;
    const int nk  = min(SLICE, K - k0);

    {
        int t = threadIdx.x;
        if (t < SLICE) {
            if (t < nk) sA[t] = gA[k0 + t];
        } else if (t < 2*SLICE) {
            int j = t - SLICE;
            if (j < nk) sB[j] = gB[k0 + j];
        }
    }
    __syncthreads();

    float2 p2 = *(const float2*)(p_rays + 2*ray);
    float2 u2 = *(const float2*)(u_rays + 2*ray);
    const float p0 = p2.x, p1 = p2.y;
    const float u0 = u2.x, u1 = u2.y;

    // a-dot coefficients (unscaled)
    const float qu0 = u0*u0, qu1 = 2.0f*u0*u1, qu2 = u1*u1;

    // b~ coefficients, scaled by s = sqrt(-L)
    const float bq0  =  SQRT_HALF_LOG2E * u0*p0;
    const float bq1  =  SQRT_HALF_LOG2E * (u0*p1 + u1*p0);
    const float bq2  =  SQRT_HALF_LOG2E * u1*p1;
    const float nbu0 = -SQRT_HALF_LOG2E * u0;
    const float nbu1 = -SQRT_HALF_LOG2E * u1;

    // c0 coefficients, scaled by L (constant term comes from sA[j].w)
    const float cq0 =  NEG_HALF_LOG2E * p0*p0;
    const float cq1 =  NEG_HALF_LOG2E * 2.0f*p0*p1;
    const float cq2 =  NEG_HALF_LOG2E * p1*p1;
    const float cp0 = -2.0f*NEG_HALF_LOG2E * p0;
    const float cp1 = -2.0f*NEG_HALF_LOG2E * p1;

    float acc = 0.0f;

    #pragma unroll 8
    for (int j = 0; j < nk; ++j) {
        float4 ga = sA[j];   // uniform address -> LDS broadcast
        float2 gb = sB[j];

        float a   = fmaf(qu2, ga.z, fmaf(qu1, ga.y, qu0 * ga.x));
        float bt  = fmaf(nbu1, gb.y, fmaf(nbu0, gb.x,
                    fmaf(bq2, ga.z, fmaf(bq1, ga.y, bq0 * ga.x))));
        float c2  = fmaf(cp1, gb.y, fmaf(cp0, gb.x,
                    fmaf(cq2, ga.z, fmaf(cq1, ga.y, fmaf(cq0, ga.x, ga.w)))));

        float ra  = __builtin_amdgcn_rsqf(a);
        float t1  = bt * ra;
        float arg = fmaf(t1, t1, c2);
        float e   = __builtin_amdgcn_exp2f(arg);
        acc = fmaf(ra, e, acc);
    }

    atomicAdd(&out[ray], acc);
}

// ---------------------------------------------------------------------------
extern "C" void kernel_launch(void* const* d_in, const int* in_sizes, int n_in,
                              void* d_out, int out_size, void* d_ws, size_t ws_size,
                              hipStream_t stream)
{
    const float* pos_raw   = (const float*)d_in[0];
    const float* conc_raw  = (const float*)d_in[1];
    const float* scale_raw = (const float*)d_in[2];
    const float* rot_raw   = (const float*)d_in[3];
    const float* p_rays    = (const float*)d_in[4];
    const float* u_rays    = (const float*)d_in[5];
    const void*  map_size  = d_in[6];

    const int K = in_sizes[1];          // conc_raw is (K,)
    const int R = out_size;             // output is (R,)

    float* out = (float*)d_out;
    float4* gA = (float4*)d_ws;                       // K float4
    float2* gB = (float2*)((float4*)d_ws + K);        // K float2  (24*K bytes)

    {
        dim3 grid((K + BLOCK - 1) / BLOCK);
        precompute_gauss<<<grid, BLOCK, 0, stream>>>(pos_raw, conc_raw, scale_raw,
                                                     rot_raw, map_size, gA, gB,
                                                     out, K, R);
    }
    {
        dim3 grid(R / BLOCK, (K + SLICE - 1) / SLICE);
        splat_main<<<grid, BLOCK, 0, stream>>>(p_rays, u_rays, gA, gB, out, K);
    }
}

// Round 4
// 25.138 us; speedup vs baseline: 1.8501x; 1.0507x over previous
//
#include <hip/hip_runtime.h>
#include <hip/hip_bf16.h>

#define EPS 1e-07f

#define BLOCK 256
#define SLICE 64            // Gaussians per K-slice (grid.y); must be even

// L = -0.5 * log2(e); s = sqrt(-L); log2(sqrt(2*pi))
#define NEG_HALF_LOG2E  (-0.72134752044448170f)
#define SQRT_HALF_LOG2E ( 0.84932180028801904f)
#define LOG2_SQRT_2PI   ( 1.32574806473616588f)

typedef float v2f __attribute__((ext_vector_type(2)));
typedef float v4f __attribute__((ext_vector_type(4)));

// ---------------------------------------------------------------------------
// Kernel 1: per-Gaussian precompute (K threads) + zero d_out.
// Pair-interleaved SoA layout (t = k>>1, h = k&1):
//   gP[t] = {m00_2t, m00_2t+1, m01_2t, m01_2t+1}
//   gQ[t] = {m11_2t, m11_2t+1, cc_2t,  cc_2t+1}    cc = L*mSm + log2(conc*sqrt(2pi))
//   gR[t] = {Sm0_2t, Sm0_2t+1, Sm1_2t, Sm1_2t+1}
// ---------------------------------------------------------------------------
__global__ void precompute_gauss(const float* __restrict__ pos_raw,
                                 const float* __restrict__ conc_raw,
                                 const float* __restrict__ scale_raw,
                                 const float* __restrict__ rot_raw,
                                 const void*  __restrict__ map_size_p,
                                 float* __restrict__ gP,
                                 float* __restrict__ gQ,
                                 float* __restrict__ gR,
                                 float* __restrict__ out,
                                 int K, int R)
{
    int k = blockIdx.x * blockDim.x + threadIdx.x;
    int nthreads = gridDim.x * blockDim.x;

    // Zero the output (replaces hipMemsetAsync dispatch).
    for (int i = k; i < R; i += nthreads) out[i] = 0.0f;

    if (k >= K) return;

    // map_size may arrive as int32 or float32 single-element array.
    unsigned int msbits = *(const unsigned int*)map_size_p;
    float msf = __uint_as_float(msbits);
    float ms;
    if (msf >= 1e-3f && msf <= 1e9f) ms = msf;
    else                             ms = (float)(*(const int*)map_size_p);

    float pr0 = pos_raw[2*k],  pr1 = pos_raw[2*k+1];
    float pos0 = ms / (1.0f + expf(-pr0));   // sigmoid * map_size
    float pos1 = ms / (1.0f + expf(-pr1));

    float cr = conc_raw[k];
    float conc = fmaxf(cr, 0.0f) + log1pf(expf(-fabsf(cr)));   // stable softplus

    float s0 = expf(scale_raw[2*k]);
    float s1 = expf(scale_raw[2*k+1]);
    float d0 = 1.0f / (s0*s0 + EPS);
    float d1 = 1.0f / (s1*s1 + EPS);

    float rot = rot_raw[k];
    float c = cosf(rot), s = sinf(rot);

    float m00 = c*c*d0 + s*s*d1;
    float m01 = c*s*(d0 - d1);
    float m11 = s*s*d0 + c*c*d1;

    float Sm0 = m00*pos0 + m01*pos1;
    float Sm1 = m01*pos0 + m11*pos1;
    float mSm = pos0*Sm0 + pos1*Sm1;

    float cc = NEG_HALF_LOG2E * mSm + log2f(conc) + LOG2_SQRT_2PI;

    int t = k >> 1, h = k & 1;
    gP[4*t + h]     = m00;  gP[4*t + 2 + h] = m01;
    gQ[4*t + h]     = m11;  gQ[4*t + 2 + h] = cc;
    gR[4*t + h]     = Sm0;  gR[4*t + 2 + h] = Sm1;
}

// ---------------------------------------------------------------------------
// Kernel 2: main pairwise accumulation, 2 Gaussians/iteration via packed f32
// (v_pk_fma_f32). Per 2 pairs: 16 pk + 4 trans + 3 ds_read_b128.
//   dens = rsqrt(a) * 2^( cc + L*c0_part + (b~ * rsqrt(a))^2 )
// ---------------------------------------------------------------------------
__global__ __launch_bounds__(BLOCK) void splat_main(
        const float* __restrict__ p_rays,
        const float* __restrict__ u_rays,
        const float4* __restrict__ gP,
        const float4* __restrict__ gQ,
        const float4* __restrict__ gR,
        float* __restrict__ out,
        int K)
{
    __shared__ v4f sP[SLICE/2];
    __shared__ v4f sQ[SLICE/2];
    __shared__ v4f sR[SLICE/2];

    const int ray = blockIdx.x * BLOCK + threadIdx.x;
    const int k0  = blockIdx.y * SLICE;
    const int np  = min(SLICE, K - k0) >> 1;    // Gaussian pairs in this slice
    const int tb  = k0 >> 1;

    {
        int t = threadIdx.x;
        if (t < SLICE/2) {
            if (t < np) { float4 v = gP[tb + t]; sP[t] = (v4f){v.x,v.y,v.z,v.w}; }
        } else if (t < SLICE) {
            int j = t - SLICE/2;
            if (j < np) { float4 v = gQ[tb + j]; sQ[j] = (v4f){v.x,v.y,v.z,v.w}; }
        } else if (t < 3*SLICE/2) {
            int j = t - SLICE;
            if (j < np) { float4 v = gR[tb + j]; sR[j] = (v4f){v.x,v.y,v.z,v.w}; }
        }
    }
    __syncthreads();

    float2 p2 = *(const float2*)(p_rays + 2*ray);
    float2 u2 = *(const float2*)(u_rays + 2*ray);
    const float p0 = p2.x, p1 = p2.y;
    const float u0 = u2.x, u1 = u2.y;

    // Ray-side coefficients, splat to both pk lanes.
    const v2f qu0 = u0*u0, qu1 = 2.0f*u0*u1, qu2 = u1*u1;

    const v2f bq0  =  SQRT_HALF_LOG2E * (u0*p0);
    const v2f bq1  =  SQRT_HALF_LOG2E * (u0*p1 + u1*p0);
    const v2f bq2  =  SQRT_HALF_LOG2E * (u1*p1);
    const v2f nbu0 = -SQRT_HALF_LOG2E * u0;
    const v2f nbu1 = -SQRT_HALF_LOG2E * u1;

    const v2f cq0 =  NEG_HALF_LOG2E * (p0*p0);
    const v2f cq1 =  NEG_HALF_LOG2E * (2.0f*p0*p1);
    const v2f cq2 =  NEG_HALF_LOG2E * (p1*p1);
    const v2f cp0 = -2.0f*NEG_HALF_LOG2E * p0;
    const v2f cp1 = -2.0f*NEG_HALF_LOG2E * p1;

    v2f acc2 = (v2f){0.0f, 0.0f};

    #pragma unroll 4
    for (int t = 0; t < np; ++t) {
        v4f P = sP[t];      // uniform address -> LDS broadcast
        v4f Q = sQ[t];
        v4f R = sR[t];

        v2f m00 = P.xy, m01 = P.zw;
        v2f m11 = Q.xy, cc  = Q.zw;
        v2f S0  = R.xy, S1  = R.zw;

        v2f a  = __builtin_elementwise_fma(qu2, m11,
                 __builtin_elementwise_fma(qu1, m01, qu0 * m00));
        v2f bt = __builtin_elementwise_fma(nbu1, S1,
                 __builtin_elementwise_fma(nbu0, S0,
                 __builtin_elementwise_fma(bq2, m11,
                 __builtin_elementwise_fma(bq1, m01, bq0 * m00))));
        v2f c2 = __builtin_elementwise_fma(cq0, m00,
                 __builtin_elementwise_fma(cq1, m01,
                 __builtin_elementwise_fma(cq2, m11,
                 __builtin_elementwise_fma(cp0, S0,
                 __builtin_elementwise_fma(cp1, S1, cc)))));

        v2f ra;
        ra.x = __builtin_amdgcn_rsqf(a.x);
        ra.y = __builtin_amdgcn_rsqf(a.y);

        v2f t1  = bt * ra;
        v2f arg = __builtin_elementwise_fma(t1, t1, c2);

        v2f e;
        e.x = __builtin_amdgcn_exp2f(arg.x);
        e.y = __builtin_amdgcn_exp2f(arg.y);

        acc2 = __builtin_elementwise_fma(ra, e, acc2);
    }

    atomicAdd(&out[ray], acc2.x + acc2.y);
}

// ---------------------------------------------------------------------------
extern "C" void kernel_launch(void* const* d_in, const int* in_sizes, int n_in,
                              void* d_out, int out_size, void* d_ws, size_t ws_size,
                              hipStream_t stream)
{
    const float* pos_raw   = (const float*)d_in[0];
    const float* conc_raw  = (const float*)d_in[1];
    const float* scale_raw = (const float*)d_in[2];
    const float* rot_raw   = (const float*)d_in[3];
    const float* p_rays    = (const float*)d_in[4];
    const float* u_rays    = (const float*)d_in[5];
    const void*  map_size  = d_in[6];

    const int K = in_sizes[1];          // conc_raw is (K,)
    const int R = out_size;             // output is (R,)

    float* out = (float*)d_out;
    float* gP = (float*)d_ws;           // K/2 float4 = 2K floats each
    float* gQ = gP + 2*K;
    float* gR = gQ + 2*K;               // total 24*K bytes

    {
        dim3 grid((K + BLOCK - 1) / BLOCK);
        precompute_gauss<<<grid, BLOCK, 0, stream>>>(pos_raw, conc_raw, scale_raw,
                                                     rot_raw, map_size,
                                                     gP, gQ, gR, out, K, R);
    }
    {
        dim3 grid(R / BLOCK, (K + SLICE - 1) / SLICE);
        splat_main<<<grid, BLOCK, 0, stream>>>(p_rays, u_rays,
                                               (const float4*)gP,
                                               (const float4*)gQ,
                                               (const float4*)gR, out, K);
    }
}

// Round 5
// 21.423 us; speedup vs baseline: 2.1709x; 1.1734x over previous
//
#include <hip/hip_runtime.h>
#include <hip/hip_bf16.h>

#define EPS 1e-07f

#define BLOCK 256
#define SLICE 64            // Gaussians per K-slice (grid.y); multiple of 4

// sqrt(0.5*log2(e)) ; log2(sqrt(2*pi))
#define SQRT_HALF_LOG2E 0.84932180028801904f
#define LOG2_SQRT_2PI   1.32574806473616588f

typedef float v4f __attribute__((ext_vector_type(4)));

// ---------------------------------------------------------------------------
// Kernel 1: per-Gaussian precompute (K threads) + zero d_out.
// Cross-product identity: c0 - b^2/a = (u x (p-pos))^2 / a',  a' = u^T(S/detS)u
// gF row-major [6][K]:
//   row 0..2 : m00' m01' m11'  (S/detS)
//   row 3    : cc = log2(conc) + log2(sqrt(2pi)) - 0.5*log2(detS)
//   row 4..5 : pos0 pos1
// ---------------------------------------------------------------------------
__global__ void precompute_gauss(const float* __restrict__ pos_raw,
                                 const float* __restrict__ conc_raw,
                                 const float* __restrict__ scale_raw,
                                 const float* __restrict__ rot_raw,
                                 const void*  __restrict__ map_size_p,
                                 float* __restrict__ gF,
                                 float* __restrict__ out,
                                 int K, int R)
{
    int k = blockIdx.x * blockDim.x + threadIdx.x;
    int nthreads = gridDim.x * blockDim.x;

    // Zero the output (replaces a memset dispatch; ordered before splat_main).
    for (int i = k; i < R; i += nthreads) out[i] = 0.0f;

    if (k >= K) return;

    // map_size may arrive as int32 or float32 single-element array.
    unsigned int msbits = *(const unsigned int*)map_size_p;
    float msf = __uint_as_float(msbits);
    float ms;
    if (msf >= 1e-3f && msf <= 1e9f) ms = msf;
    else                             ms = (float)(*(const int*)map_size_p);

    float pr0 = pos_raw[2*k],  pr1 = pos_raw[2*k+1];
    float pos0 = ms / (1.0f + expf(-pr0));   // sigmoid * map_size
    float pos1 = ms / (1.0f + expf(-pr1));

    float cr = conc_raw[k];
    float conc = fmaxf(cr, 0.0f) + log1pf(expf(-fabsf(cr)));   // stable softplus

    float s0 = expf(scale_raw[2*k]);
    float s1 = expf(scale_raw[2*k+1]);
    float d0 = 1.0f / (s0*s0 + EPS);
    float d1 = 1.0f / (s1*s1 + EPS);

    float rot = rot_raw[k];
    float c = cosf(rot), s = sinf(rot);

    float m00 = c*c*d0 + s*s*d1;
    float m01 = c*s*(d0 - d1);
    float m11 = s*s*d0 + c*c*d1;

    float det    = d0 * d1;            // detS
    float invdet = 1.0f / det;

    float cc = log2f(conc) + LOG2_SQRT_2PI - 0.5f * log2f(det);

    gF[0*K + k] = m00 * invdet;
    gF[1*K + k] = m01 * invdet;
    gF[2*K + k] = m11 * invdet;
    gF[3*K + k] = cc;
    gF[4*K + k] = pos0;
    gF[5*K + k] = pos1;
}

// ---------------------------------------------------------------------------
// Kernel 2: main pairwise accumulation.
//   t   = (w~ + u~1*pos0 - u~0*pos1) * rsqrt(a')
//   out+= rsqrt(a') * 2^( cc - t^2 )
// 7 VALU + 2 trans per pair; 6 broadcast ds_read_b128 per 4 Gaussians.
// ---------------------------------------------------------------------------
__global__ __launch_bounds__(BLOCK) void splat_main(
        const float* __restrict__ p_rays,
        const float* __restrict__ u_rays,
        const float* __restrict__ gF,
        float* __restrict__ out,
        int K)
{
    __shared__ float sF[6][SLICE];

    const int ray = blockIdx.x * BLOCK + threadIdx.x;
    const int k0  = blockIdx.y * SLICE;
    const int nk  = min(SLICE, K - k0);

    // Stage the slice, SoA rows (broadcast-friendly, coalesced 256B runs).
    for (int i = threadIdx.x; i < 6*SLICE; i += BLOCK) {
        int f = i >> 6;             // SLICE == 64
        int c = i & (SLICE - 1);
        if (c < nk) sF[f][c] = gF[f*K + k0 + c];
    }
    __syncthreads();

    float2 p2 = *(const float2*)(p_rays + 2*ray);
    float2 u2 = *(const float2*)(u_rays + 2*ray);
    const float p0 = p2.x, p1 = p2.y;
    const float u0 = u2.x, u1 = u2.y;

    const float qu0 = u0*u0, qu1 = 2.0f*u0*u1, qu2 = u1*u1;

    // scaled by sqrt(0.5*log2 e) so arg = cc - t^2 directly in log2 domain
    const float wt   =  SQRT_HALF_LOG2E * (u0*p1 - u1*p0);
    const float ut1  =  SQRT_HALF_LOG2E * u1;
    const float nut0 = -SQRT_HALF_LOG2E * u0;

    float acc = 0.0f;

    const int nk4 = nk & ~3;
    for (int t4 = 0; t4 < nk4; t4 += 4) {
        v4f M00 = *(const v4f*)&sF[0][t4];   // uniform address -> broadcast
        v4f M01 = *(const v4f*)&sF[1][t4];
        v4f M11 = *(const v4f*)&sF[2][t4];
        v4f CC  = *(const v4f*)&sF[3][t4];
        v4f P0  = *(const v4f*)&sF[4][t4];
        v4f P1  = *(const v4f*)&sF[5][t4];

        #pragma unroll
        for (int g = 0; g < 4; ++g) {
            float a  = fmaf(qu2, M11[g], fmaf(qu1, M01[g], qu0 * M00[g]));
            float cr = fmaf(nut0, P1[g], fmaf(ut1, P0[g], wt));
            float ra = __builtin_amdgcn_rsqf(a);
            float t  = cr * ra;
            float ar = fmaf(-t, t, CC[g]);
            float e  = __builtin_amdgcn_exp2f(ar);
            acc = fmaf(ra, e, acc);
        }
    }
    // tail (not taken for K % SLICE == 0)
    for (int j = nk4; j < nk; ++j) {
        float a  = fmaf(qu2, sF[2][j], fmaf(qu1, sF[1][j], qu0 * sF[0][j]));
        float cr = fmaf(nut0, sF[5][j], fmaf(ut1, sF[4][j], wt));
        float ra = __builtin_amdgcn_rsqf(a);
        float t  = cr * ra;
        float ar = fmaf(-t, t, sF[3][j]);
        float e  = __builtin_amdgcn_exp2f(ar);
        acc = fmaf(ra, e, acc);
    }

    atomicAdd(&out[ray], acc);
}

// ---------------------------------------------------------------------------
extern "C" void kernel_launch(void* const* d_in, const int* in_sizes, int n_in,
                              void* d_out, int out_size, void* d_ws, size_t ws_size,
                              hipStream_t stream)
{
    const float* pos_raw   = (const float*)d_in[0];
    const float* conc_raw  = (const float*)d_in[1];
    const float* scale_raw = (const float*)d_in[2];
    const float* rot_raw   = (const float*)d_in[3];
    const float* p_rays    = (const float*)d_in[4];
    const float* u_rays    = (const float*)d_in[5];
    const void*  map_size  = d_in[6];

    const int K = in_sizes[1];          // conc_raw is (K,)
    const int R = out_size;             // output is (R,)

    float* out = (float*)d_out;
    float* gF  = (float*)d_ws;          // 6*K floats

    {
        dim3 grid((K + BLOCK - 1) / BLOCK);
        precompute_gauss<<<grid, BLOCK, 0, stream>>>(pos_raw, conc_raw, scale_raw,
                                                     rot_raw, map_size,
                                                     gF, out, K, R);
    }
    {
        dim3 grid(R / BLOCK, (K + SLICE - 1) / SLICE);
        splat_main<<<grid, BLOCK, 0, stream>>>(p_rays, u_rays, gF, out, K);
    }
}